// Round 1
// baseline (181.982 us; speedup 1.0000x reference)
//
#include <hip/hip_runtime.h>

// Problem constants (B=2, T=2048, D=1024, H=16, L=12, DH=64)
#define TT 2048
#define DD 1024
#define HHEADS 16
#define LLEV 12
#define MTOT 4096   // B*T

typedef float f32x4 __attribute__((ext_vector_type(4)));

__device__ __forceinline__ unsigned short f2bf(float f) {
  union { float f; unsigned u; } c; c.f = f;
  return (unsigned short)((c.u + 0x7fffu + ((c.u >> 16) & 1u)) >> 16);
}

// bf16 16x16x32 MFMA via inline asm: d += a*b (a,b are 8 bf16 in 4 VGPRs).
__device__ __forceinline__ void mfma16(f32x4& d, f32x4 a, f32x4 b) {
  asm("v_mfma_f32_16x16x32_bf16 %0, %1, %2, %0" : "+v"(d) : "v"(a), "v"(b));
}

// async global->LDS, 16B per lane; lds must be wave-uniform base.
__device__ __forceinline__ void gld16(void* lds, const void* g) {
  __builtin_amdgcn_global_load_lds(
      (const __attribute__((address_space(1))) unsigned int*)g,
      (__attribute__((address_space(3))) unsigned int*)lds, 16, 0, 0);
}

// wait states before VALU reads MFMA results (inline-asm mfma is opaque to
// the compiler's hazard recognizer)
__device__ __forceinline__ void mfma_fence() {
  asm volatile("s_nop 7\n\ts_nop 7\n\ts_nop 7");
}

// ---------------- small prep kernels ----------------

__global__ void cast_x_kernel(const float* __restrict__ x, unsigned short* __restrict__ xbf) {
  int i = blockIdx.x * 256 + threadIdx.x;   // one float4 per thread, exact grid
  float4 v = ((const float4*)x)[i];
  ushort4 o; o.x = f2bf(v.x); o.y = f2bf(v.y); o.z = f2bf(v.z); o.w = f2bf(v.w);
  ((ushort4*)xbf)[i] = o;
}

// W [1024][N] fp32 -> Wt [N][1024] bf16
__global__ void transpose_cast_w(const float* __restrict__ W, unsigned short* __restrict__ Wt, int N) {
  __shared__ float tile[32][33];
  int n0 = blockIdx.x * 32, k0 = blockIdx.y * 32;
  int tx = threadIdx.x, ty = threadIdx.y;  // 32 x 8
#pragma unroll
  for (int i = 0; i < 4; ++i) tile[ty + i * 8][tx] = W[(k0 + ty + i * 8) * N + n0 + tx];
  __syncthreads();
#pragma unroll
  for (int i = 0; i < 4; ++i) Wt[(n0 + ty + i * 8) * 1024 + k0 + tx] = f2bf(tile[tx][ty + i * 8]);
}

// ---------------- GEMM: C = A[4096,1024] * Bt[N,1024]^T + bias ----------------
// MODE 0: bf16 out, [B,H,T,DH] permuted store (Q,K)
// MODE 1: bf16 out, [B,H,DH,T] transposed store (V^T), packed 8B
// MODE 2: fp32 softplus out, [B,H,T,L] store (lam), Nreal guard
// MODE 3: fp32 out, row-major [4096,1024] (final output)
template <int MODE>
__global__ __launch_bounds__(256, 2) void gemm_bt(
    const unsigned short* __restrict__ A, const unsigned short* __restrict__ Bt,
    const float* __restrict__ bias, void* __restrict__ out, int Nreal) {
  __shared__ unsigned short As[128 * 64];
  __shared__ unsigned short Bs[128 * 64];
  const int tid = threadIdx.x;
  const int wid = tid >> 6, lane = tid & 63, l16 = lane & 15, g = lane >> 4;
  const int wm = wid >> 1, wn = wid & 1;
  const int m0 = blockIdx.y * 128, n0 = blockIdx.x * 128;
  const int rowlane = lane >> 3;             // 0..7
  const int swz = (lane & 7) ^ rowlane;      // source-chunk pre-swizzle (T21)

  f32x4 acc[4][4] = {};

  for (int kb = 0; kb < 16; ++kb) {
    __syncthreads();
#pragma unroll
    for (int i = 0; i < 4; ++i) {
      int c = wid * 4 + i;                   // 1KB chunk id, rows c*8..c*8+7
      int row = c * 8 + rowlane;
      gld16((char*)As + c * 1024, A + (m0 + row) * 1024 + kb * 64 + swz * 8);
      gld16((char*)Bs + c * 1024, Bt + (n0 + row) * 1024 + kb * 64 + swz * 8);
    }
    __syncthreads();
#pragma unroll
    for (int kk = 0; kk < 2; ++kk) {
      f32x4 a[4], b[4];
#pragma unroll
      for (int f = 0; f < 4; ++f) {
        int ra = wm * 64 + f * 16 + l16;
        a[f] = *(const f32x4*)((const char*)As + ra * 128 + (((kk * 4 + g) ^ (ra & 7)) << 4));
        int rb = wn * 64 + f * 16 + l16;
        b[f] = *(const f32x4*)((const char*)Bs + rb * 128 + (((kk * 4 + g) ^ (rb & 7)) << 4));
      }
#pragma unroll
      for (int mf = 0; mf < 4; ++mf)
#pragma unroll
        for (int nf = 0; nf < 4; ++nf) mfma16(acc[mf][nf], a[mf], b[nf]);
    }
  }
  mfma_fence();

  // epilogue: m = m0+wm*64+mf*16+g*4+r ; n = n0+wn*64+nf*16+l16
#pragma unroll
  for (int nf = 0; nf < 4; ++nf) {
    int n = n0 + wn * 64 + nf * 16 + l16;
    float bv = (MODE == 2) ? (n < Nreal ? bias[n] : 0.f) : bias[n];
#pragma unroll
    for (int mf = 0; mf < 4; ++mf) {
      int m = m0 + wm * 64 + mf * 16 + g * 4;
      int bb = m >> 11, t = m & 2047;
      f32x4 v = acc[mf][nf];
      if (MODE == 0) {
        unsigned short* dst = (unsigned short*)out + ((((bb << 4) + (n >> 6)) << 11) + t) * 64 + (n & 63);
#pragma unroll
        for (int r = 0; r < 4; ++r) dst[r * 64] = f2bf(v[r] + bv);
      } else if (MODE == 1) {
        ushort4 pk;
        pk.x = f2bf(v[0] + bv); pk.y = f2bf(v[1] + bv);
        pk.z = f2bf(v[2] + bv); pk.w = f2bf(v[3] + bv);
        *(ushort4*)((unsigned short*)out + ((((bb << 4) + (n >> 6)) << 6) + (n & 63)) * 2048 + t) = pk;
      } else if (MODE == 2) {
        if (n < Nreal) {
          int h = n / 12, l = n - h * 12;
          float* dst = (float*)out + ((((bb << 4) + h) << 11) + t) * 12 + l;
#pragma unroll
          for (int r = 0; r < 4; ++r) {
            float s = v[r] + bv;
            dst[r * 12] = fmaxf(s, 0.f) + log1pf(expf(-fabsf(s)));
          }
        }
      } else {
        float* dst = (float*)out + (m << 10) + n;
#pragma unroll
        for (int r = 0; r < 4; ++r) dst[r << 10] = v[r] + bv;
      }
    }
  }
}

// ---------------- Fenwick-masked attention ----------------
// O = (M o Q K^T) V per (b,h); M[tq,ti] = lam[tq][31-clz((tq+1)^ti)], ti<=tq.
// grid (T/64, B*H), 4 waves; wave owns 16 q rows; 64-key blocks via LDS.
__global__ __launch_bounds__(256, 2) void attn_fenwick(
    const unsigned short* __restrict__ Qp, const unsigned short* __restrict__ Kp,
    const unsigned short* __restrict__ Vt, const float* __restrict__ lamp,
    unsigned short* __restrict__ Y) {
  __shared__ unsigned short Ks[64 * 64];
  __shared__ unsigned short Vs[64 * 64];
  __shared__ unsigned short Ps[4][16 * 64];
  __shared__ float laml[64 * 12];

  const int tid = threadIdx.x;
  const int wid = tid >> 6, lane = tid & 63, l16 = lane & 15, g = lane >> 4;
  const int blkq = blockIdx.x, bh = blockIdx.y;
  const int tq = blkq * 64 + wid * 16 + l16;

  for (int i = tid; i < 64 * 12; i += 256) laml[i] = lamp[(bh * TT + blkq * 64) * 12 + i];

  // Q fragments (B-operand): lane holds Q[q=l16][k-chunk], 16B each
  const unsigned short* Qrow = Qp + (bh * TT + tq) * 64;
  f32x4 qf0 = *(const f32x4*)(Qrow + g * 8);
  f32x4 qf1 = *(const f32x4*)(Qrow + 32 + g * 8);

  f32x4 o0 = {0,0,0,0}, o1 = {0,0,0,0}, o2 = {0,0,0,0}, o3 = {0,0,0,0};
  const int rowlane = lane >> 3, swz = (lane & 7) ^ rowlane;
  char* PsW = (char*)&Ps[wid][0];
  const float* lrow = &laml[(wid * 16 + l16) * 12];

  for (int kb = 0; kb <= blkq; ++kb) {
    __syncthreads();
#pragma unroll
    for (int i = 0; i < 2; ++i) {
      int c = wid * 2 + i;
      int row = c * 8 + rowlane;
      gld16((char*)Ks + c * 1024, Kp + (bh * TT + kb * 64 + row) * 64 + swz * 8);
      gld16((char*)Vs + c * 1024, Vt + (bh * 64 + row) * TT + kb * 64 + swz * 8);
    }
    __syncthreads();

    // S^T = K * Q^T : lane owns q=l16, keys = kf*16 + g*4 + r
    f32x4 s[4] = {};
#pragma unroll
    for (int kk = 0; kk < 2; ++kk) {
      f32x4 q = kk ? qf1 : qf0;
#pragma unroll
      for (int kf = 0; kf < 4; ++kf) {
        int row = kf * 16 + l16;
        f32x4 kfr = *(const f32x4*)((const char*)Ks + row * 128 + (((kk * 4 + g) ^ (row & 7)) << 4));
        mfma16(s[kf], kfr, q);
      }
    }
    mfma_fence();

    // mask -> P (bf16) into per-wave LDS, swizzled [q][key] rows of 128B
    if (kb < blkq) {
      int lvl = 37 - __clz(((tq + 1) >> 6) ^ kb);  // block-constant level per lane
      float w = lrow[lvl];
#pragma unroll
      for (int kf = 0; kf < 4; ++kf) {
        ushort4 pk;
        pk.x = f2bf(s[kf][0] * w); pk.y = f2bf(s[kf][1] * w);
        pk.z = f2bf(s[kf][2] * w); pk.w = f2bf(s[kf][3] * w);
        *(ushort4*)(PsW + l16 * 128 + (((kf * 2 + (g >> 1)) ^ (l16 & 7)) << 4) + ((g & 1) << 3)) = pk;
      }
    } else {  // diagonal block: per-element level + causal zero
#pragma unroll
      for (int kf = 0; kf < 4; ++kf) {
        float p[4];
#pragma unroll
        for (int r = 0; r < 4; ++r) {
          int ti = kb * 64 + kf * 16 + g * 4 + r;
          p[r] = (ti <= tq) ? s[kf][r] * lrow[31 - __clz((tq + 1) ^ ti)] : 0.f;
        }
        ushort4 pk;
        pk.x = f2bf(p[0]); pk.y = f2bf(p[1]); pk.z = f2bf(p[2]); pk.w = f2bf(p[3]);
        *(ushort4*)(PsW + l16 * 128 + (((kf * 2 + (g >> 1)) ^ (l16 & 7)) << 4) + ((g & 1) << 3)) = pk;
      }
    }
    asm volatile("" ::: "memory");  // order P LDS writes vs typed re-reads

    // O^T += V^T * P^T  (per-wave; same-wave LDS ops are in order)
    f32x4 pf0 = *(const f32x4*)(PsW + l16 * 128 + (((0 + g) ^ (l16 & 7)) << 4));
    f32x4 pf1 = *(const f32x4*)(PsW + l16 * 128 + (((4 + g) ^ (l16 & 7)) << 4));
#pragma unroll
    for (int df = 0; df < 4; ++df) {
      int row = df * 16 + l16;
      f32x4 v0 = *(const f32x4*)((const char*)Vs + row * 128 + (((0 + g) ^ (row & 7)) << 4));
      f32x4 v1 = *(const f32x4*)((const char*)Vs + row * 128 + (((4 + g) ^ (row & 7)) << 4));
      f32x4& od = (df == 0) ? o0 : (df == 1) ? o1 : (df == 2) ? o2 : o3;
      mfma16(od, v0, pf0);
      mfma16(od, v1, pf1);
    }
  }
  mfma_fence();

  // store Y[b*T+tq][h*64 + dh], dh = df*16 + g*4 + r (4 consecutive -> 8B)
  int b = bh >> 4, h = bh & 15;
  unsigned short* yrow = Y + (b * TT + tq) * DD + h * 64;
#pragma unroll
  for (int df = 0; df < 4; ++df) {
    f32x4 od = (df == 0) ? o0 : (df == 1) ? o1 : (df == 2) ? o2 : o3;
    ushort4 pk;
    pk.x = f2bf(od[0]); pk.y = f2bf(od[1]); pk.z = f2bf(od[2]); pk.w = f2bf(od[3]);
    *(ushort4*)(yrow + df * 16 + g * 4) = pk;
  }
}

// ---------------- host ----------------

extern "C" void kernel_launch(void* const* d_in, const int* in_sizes, int n_in,
                              void* d_out, int out_size, void* d_ws, size_t ws_size,
                              hipStream_t stream) {
  const float* x  = (const float*)d_in[0];
  const float* Wq = (const float*)d_in[1];
  const float* bq = (const float*)d_in[2];
  const float* Wk = (const float*)d_in[3];
  const float* bk = (const float*)d_in[4];
  const float* Wv = (const float*)d_in[5];
  const float* bv = (const float*)d_in[6];
  const float* Wl = (const float*)d_in[7];
  const float* bl = (const float*)d_in[8];
  const float* Wo = (const float*)d_in[9];
  const float* bo = (const float*)d_in[10];

  char* ws = (char*)d_ws;
  size_t off = 0;
  auto alloc = [&](size_t bytes) { char* p = ws + off; off += bytes; return p; };

  unsigned short* xbf  = (unsigned short*)alloc((size_t)MTOT * DD * 2);       // 8 MB
  unsigned short* Wqt  = (unsigned short*)alloc((size_t)DD * DD * 2);
  unsigned short* Wkt  = (unsigned short*)alloc((size_t)DD * DD * 2);
  unsigned short* Wvt  = (unsigned short*)alloc((size_t)DD * DD * 2);
  unsigned short* Wot  = (unsigned short*)alloc((size_t)DD * DD * 2);
  unsigned short* Wlt  = (unsigned short*)alloc((size_t)256 * DD * 2);        // padded to 256 rows
  unsigned short* Qp   = (unsigned short*)alloc((size_t)MTOT * DD * 2);       // [B,H,T,DH]
  unsigned short* Kp   = (unsigned short*)alloc((size_t)MTOT * DD * 2);
  unsigned short* Vtb  = (unsigned short*)alloc((size_t)MTOT * DD * 2);       // [B,H,DH,T]
  float*          lamp = (float*)alloc((size_t)2 * HHEADS * TT * LLEV * 4);   // [B,H,T,L]
  unsigned short* Y    = (unsigned short*)alloc((size_t)MTOT * DD * 2);
  (void)ws_size; (void)off; (void)in_sizes; (void)n_in; (void)out_size;

  cast_x_kernel<<<MTOT * DD / 4 / 256, 256, 0, stream>>>(x, xbf);
  dim3 tb(32, 8);
  transpose_cast_w<<<dim3(32, 32), tb, 0, stream>>>(Wq, Wqt, 1024);
  transpose_cast_w<<<dim3(32, 32), tb, 0, stream>>>(Wk, Wkt, 1024);
  transpose_cast_w<<<dim3(32, 32), tb, 0, stream>>>(Wv, Wvt, 1024);
  transpose_cast_w<<<dim3(32, 32), tb, 0, stream>>>(Wo, Wot, 1024);
  transpose_cast_w<<<dim3(6, 32),  tb, 0, stream>>>(Wl, Wlt, 192);

  gemm_bt<0><<<dim3(8, 32), 256, 0, stream>>>(xbf, Wqt, bq, Qp, 1024);
  gemm_bt<0><<<dim3(8, 32), 256, 0, stream>>>(xbf, Wkt, bk, Kp, 1024);
  gemm_bt<1><<<dim3(8, 32), 256, 0, stream>>>(xbf, Wvt, bv, Vtb, 1024);
  gemm_bt<2><<<dim3(2, 32), 256, 0, stream>>>(xbf, Wlt, bl, lamp, 192);

  attn_fenwick<<<dim3(32, 32), 256, 0, stream>>>(Qp, Kp, Vtb, lamp, Y);

  gemm_bt<3><<<dim3(8, 32), 256, 0, stream>>>(Y, Wot, bo, (float*)d_out, 1024);
}

// Round 2
// 131.106 us; speedup vs baseline: 1.3881x; 1.3881x over previous
//
#include <hip/hip_runtime.h>

// Problem constants (B=2, T=2048, D=1024, H=16, L=12, DH=64)
#define TT 2048
#define DD 1024
#define MTOT 4096   // B*T

typedef float f32x4  __attribute__((ext_vector_type(4)));
typedef float f32x16 __attribute__((ext_vector_type(16)));

__device__ __forceinline__ unsigned short f2bf(float f) {
  union { float f; unsigned u; } c; c.f = f;
  return (unsigned short)((c.u + 0x7fffu + ((c.u >> 16) & 1u)) >> 16);
}

__device__ __forceinline__ void mfma16(f32x4& d, f32x4 a, f32x4 b) {
  asm volatile("v_mfma_f32_16x16x32_bf16 %0, %1, %2, %0" : "+v"(d) : "v"(a), "v"(b));
}
__device__ __forceinline__ void mfma32(f32x16& d, f32x4 a, f32x4 b) {
  asm volatile("v_mfma_f32_32x32x16_bf16 %0, %1, %2, %0" : "+v"(d) : "v"(a), "v"(b));
}
__device__ __forceinline__ float cvtpk(float lo, float hi) {
  float r;
  asm("v_cvt_pk_bf16_f32 %0, %1, %2" : "=v"(r) : "v"(lo), "v"(hi));
  return r;
}
__device__ __forceinline__ void plswap(float& a, float& b) {
  asm volatile("v_permlane32_swap_b32 %0, %1" : "+v"(a), "+v"(b));
}
__device__ __forceinline__ void gld16(void* lds, const void* g) {
  __builtin_amdgcn_global_load_lds(
      (const __attribute__((address_space(1))) unsigned int*)g,
      (__attribute__((address_space(3))) unsigned int*)lds, 16, 0, 0);
}
__device__ __forceinline__ void mfma_fence() {
  asm volatile("s_nop 7\n\ts_nop 7\n\ts_nop 7");
}
__device__ __forceinline__ void snop1() { asm volatile("s_nop 1"); }

// ---------------- prep kernels ----------------

__global__ void cast_x_kernel(const float* __restrict__ x, unsigned short* __restrict__ xbf) {
  int i = blockIdx.x * 256 + threadIdx.x;
  float4 v = ((const float4*)x)[i];
  ushort4 o; o.x = f2bf(v.x); o.y = f2bf(v.y); o.z = f2bf(v.z); o.w = f2bf(v.w);
  ((ushort4*)xbf)[i] = o;
}

// Fused transpose: Wcat[4352][1024] bf16 = [Wq^T;Wk^T;Wv^T;Wl^T;pad;Wo^T]
__global__ void transpose_all(const float* __restrict__ Wq, const float* __restrict__ Wk,
                              const float* __restrict__ Wv, const float* __restrict__ Wl,
                              const float* __restrict__ Wo, unsigned short* __restrict__ Wcat) {
  __shared__ float tile[32][33];
  int n0 = blockIdx.x * 32, k0 = blockIdx.y * 32;
  int tx = threadIdx.x, ty = threadIdx.y;  // 32 x 8
  const float* src; int scol = 0, sN = 1024;
  if (n0 < 1024)      { src = Wq; scol = n0; }
  else if (n0 < 2048) { src = Wk; scol = n0 - 1024; }
  else if (n0 < 3072) { src = Wv; scol = n0 - 2048; }
  else if (n0 < 3264) { src = Wl; scol = n0 - 3072; sN = 192; }
  else if (n0 < 3328) { src = nullptr; }
  else                { src = Wo; scol = n0 - 3328; }
  if (src) {
#pragma unroll
    for (int i = 0; i < 4; ++i) tile[ty + i * 8][tx] = src[(k0 + ty + i * 8) * sN + scol + tx];
  }
  __syncthreads();
#pragma unroll
  for (int i = 0; i < 4; ++i)
    Wcat[(n0 + ty + i * 8) * 1024 + k0 + tx] = src ? f2bf(tile[tx][ty + i * 8]) : (unsigned short)0;
}

// ---------------- GEMM: C = A[4096,1024] * Bt[N,1024]^T + bias ----------------
// MODE 0: fused QKVL epilogue (seg by n: Q | K | V^T | softplus-lam)
// MODE 1: fp32 out row-major [4096,1024] (final @ Wo + bo)
template <int BM, int MODE>
__global__ __launch_bounds__(256, 2) void gemm2(
    const unsigned short* __restrict__ A, const unsigned short* __restrict__ Bt,
    const float* __restrict__ b0p, const float* __restrict__ b1p,
    const float* __restrict__ b2p, const float* __restrict__ b3p,
    void* __restrict__ o0p, void* __restrict__ o1p, void* __restrict__ o2p, void* __restrict__ o3p) {
  constexpr int MF = BM / 32;                 // m-frags per wave (wave = BM/2 rows)
  __shared__ unsigned short As[BM * 64];
  __shared__ unsigned short Bs[128 * 64];
  const int tid = threadIdx.x;
  const int wid = tid >> 6, lane = tid & 63, l16 = lane & 15, g = lane >> 4;
  const int wm = wid >> 1, wn = wid & 1;
  const int m0 = blockIdx.y * BM, n0 = blockIdx.x * 128;
  const int rowlane = lane >> 3;
  const int swz = (lane & 7) ^ rowlane;

  f32x4 acc[MF][4] = {};

  for (int kb = 0; kb < 16; ++kb) {
    __syncthreads();
#pragma unroll
    for (int i = 0; i < MF; ++i) {           // A chunks: BM/8 total
      int c = wid * MF + i;
      int row = c * 8 + rowlane;
      gld16((char*)As + c * 1024, A + (size_t)(m0 + row) * 1024 + kb * 64 + swz * 8);
    }
#pragma unroll
    for (int i = 0; i < 4; ++i) {            // B chunks: 16 total
      int c = wid * 4 + i;
      int row = c * 8 + rowlane;
      gld16((char*)Bs + c * 1024, Bt + (size_t)(n0 + row) * 1024 + kb * 64 + swz * 8);
    }
    __syncthreads();
#pragma unroll
    for (int kk = 0; kk < 2; ++kk) {
      f32x4 a[MF], b[4];
#pragma unroll
      for (int f = 0; f < MF; ++f) {
        int ra = wm * (BM / 2) + f * 16 + l16;
        a[f] = *(const f32x4*)((const char*)As + ra * 128 + (((kk * 4 + g) ^ (ra & 7)) << 4));
      }
#pragma unroll
      for (int f = 0; f < 4; ++f) {
        int rb = wn * 64 + f * 16 + l16;
        b[f] = *(const f32x4*)((const char*)Bs + rb * 128 + (((kk * 4 + g) ^ (rb & 7)) << 4));
      }
#pragma unroll
      for (int mf = 0; mf < MF; ++mf)
#pragma unroll
        for (int nf = 0; nf < 4; ++nf) mfma16(acc[mf][nf], a[mf], b[nf]);
    }
  }
  mfma_fence();

  // epilogue: m = m0+wm*(BM/2)+mf*16+g*4+r ; n = n0+wn*64+nf*16+l16
#pragma unroll
  for (int nf = 0; nf < 4; ++nf) {
    int n = n0 + wn * 64 + nf * 16 + l16;
#pragma unroll
    for (int mf = 0; mf < MF; ++mf) {
      int m = m0 + wm * (BM / 2) + mf * 16 + g * 4;
      int bb = m >> 11, t = m & 2047;
      f32x4 v = acc[mf][nf];
      if (MODE == 1) {
        float bv = b0p[n];
        float* dst = (float*)o0p + ((size_t)m << 10) + n;
#pragma unroll
        for (int r = 0; r < 4; ++r) dst[(size_t)r << 10] = v[r] + bv;
      } else {
        int seg = n >> 10;                    // 0=Q 1=K 2=V 3=lam (uniform per block)
        int np = n & 1023;
        if (seg <= 1) {
          float bv = seg == 0 ? b0p[np] : b1p[np];
          unsigned short* dst = (unsigned short*)(seg == 0 ? o0p : o1p) +
              ((size_t)((bb << 4) + (np >> 6)) * TT + t) * 64 + (np & 63);
#pragma unroll
          for (int r = 0; r < 4; ++r) dst[r * 64] = f2bf(v[r] + bv);
        } else if (seg == 2) {
          float bv = b2p[np];
          ushort4 pk;
          pk.x = f2bf(v[0] + bv); pk.y = f2bf(v[1] + bv);
          pk.z = f2bf(v[2] + bv); pk.w = f2bf(v[3] + bv);
          *(ushort4*)((unsigned short*)o2p +
              ((size_t)((bb << 4) + (np >> 6)) * 64 + (np & 63)) * TT + t) = pk;
        } else if (np < 192) {
          float bv = b3p[np];
          int h = np / 12, l = np - h * 12;
          float* dst = (float*)o3p + ((size_t)((bb << 4) + h) * TT + t) * 12 + l;
#pragma unroll
          for (int r = 0; r < 4; ++r) {
            float s = v[r] + bv;
            dst[r * 12] = fmaxf(s, 0.f) + log1pf(expf(-fabsf(s)));
          }
        }
      }
    }
  }
}

// ---------------- Fenwick-masked attention v2 ----------------
// O = (M o Q K^T) V per (b,h); M[tq,ti] = lam[tq][31-clz((tq+1)^ti)], ti<=tq.
// 128-q blocks, 4 waves x 32q (32x32x16 MFMA), KVBLK=128, dbuf K/V, P in regs.
__global__ __launch_bounds__(256, 2) void attn_fenwick2(
    const unsigned short* __restrict__ Qp, const unsigned short* __restrict__ Kp,
    const unsigned short* __restrict__ Vt, const float* __restrict__ lamp,
    unsigned short* __restrict__ Y) {
  __shared__ unsigned short Ks[2][64 * 128];  // [r=key&63][h*64+d], 16-chunk XOR swz
  __shared__ unsigned short Vs[2][64 * 128];  // [d][key], 16-chunk XOR swz
  __shared__ float laml[12 * 128];            // [lvl][q] -> bank = q (conflict-free)

  const int tid = threadIdx.x;
  const int w = tid >> 6, lane = tid & 63;
  const int q5 = lane & 31, hi = lane >> 5;

  // load-balanced block mapping: pair (bx, bx+256) -> jq + (15-jq) = const work
  int bx = blockIdx.x;
  int bh, jq;
  if (bx < 256) { bh = bx >> 4; jq = bx & 15; }
  else          { bh = 16 + ((bx - 256) >> 4); jq = 15 - (bx & 15); }

  const int qloc = w * 32 + q5;
  const int tqg = jq * 128 + qloc;

  {
    const float* src = lamp + ((size_t)bh * TT + jq * 128) * 12;
    for (int i = tid; i < 1536; i += 256) {
      int q = i / 12, l = i - q * 12;
      laml[l * 128 + q] = src[i];
    }
  }

  // Q B-frags (4 k-slices of 16): lane holds Q[tq][ks*16 + hi*8 .. +8)
  f32x4 qf[4];
  {
    const unsigned short* Qrow = Qp + ((size_t)bh * TT + tqg) * 64;
#pragma unroll
    for (int ks = 0; ks < 4; ++ks) qf[ks] = *(const f32x4*)(Qrow + ks * 16 + hi * 8);
  }

  f32x16 o0 = (f32x16)0.f, o1 = (f32x16)0.f;

  const unsigned short* Kbh = Kp + (size_t)bh * (TT * 64);
  const unsigned short* Vbh = Vt + (size_t)bh * (64 * TT);

  auto stage = [&](int kb, int buf) {
#pragma unroll
    for (int i = 0; i < 4; ++i) {
      int ch = w * 4 + i;
      int o = ch * 1024 + lane * 16;
      int r = o >> 8;                // dest row
      int cp = (o >> 4) & 15;        // swizzled chunk-in-row
      {
        int c = cp ^ (r & 15);       // logical: h = c>>3, d0 = (c&7)*8
        gld16((char*)&Ks[buf][0] + ch * 1024,
              Kbh + (size_t)(kb * 128 + (c >> 3) * 64 + r) * 64 + (c & 7) * 8);
      }
      {
        int c = cp ^ (r & 15);       // logical: keys c*8..c*8+7
        gld16((char*)&Vs[buf][0] + ch * 1024,
              Vbh + (size_t)r * TT + kb * 128 + c * 8);
      }
    }
  };

  stage(0, 0);
  int cur = 0;

  for (int kb = 0; kb <= jq; ++kb) {
    __syncthreads();                 // drains vmcnt: buf[cur] staged; joins waves
    if (kb < jq) stage(kb + 1, cur ^ 1);
    const char* Kbase = (const char*)&Ks[cur][0];
    const char* Vbase = (const char*)&Vs[cur][0];
    const bool diag = (kb == jq);
    const int ntiles = diag ? (w + 1) : 4;

    // S^T = K * Q^T per 32-key tile: lane owns col q=q5, rows=keys
    f32x16 s[4];
#pragma unroll
    for (int t = 0; t < 4; ++t) {
      if (t >= ntiles) continue;
      s[t] = (f32x16)0.f;
      int r = (t & 1) * 32 + q5;
      int h = t >> 1;
#pragma unroll
      for (int ks = 0; ks < 4; ++ks) {
        int c = h * 8 + ks * 2 + hi;
        f32x4 kf = *(const f32x4*)(Kbase + r * 256 + ((c ^ (r & 15)) << 4));
        mfma32(s[t], kf, qf[ks]);
      }
    }
    mfma_fence();

#pragma unroll
    for (int t = 0; t < 4; ++t) {
      if (t >= ntiles) continue;
      int key64 = (kb << 1) + (t >> 1);
      float pkv[8];
      if (!diag || ((t >> 1) != (w >> 1))) {
        int lvl = 37 - __clz(((tqg + 1) >> 6) ^ key64);
        float wv = laml[lvl * 128 + qloc];
#pragma unroll
        for (int i = 0; i < 8; ++i)
          pkv[i] = cvtpk(s[t][2 * i] * wv, s[t][2 * i + 1] * wv);
      } else {
        // per-element level (+causal) — same 64-block
#pragma unroll
        for (int i = 0; i < 8; ++i) {
          float pe[2];
#pragma unroll
          for (int e = 0; e < 2; ++e) {
            int reg = 2 * i + e;
            int tig = kb * 128 + t * 32 + (reg & 3) + 8 * (reg >> 2) + 4 * hi;
            float pv = 0.f;
            if (tig <= tqg) {
              int lvl = 31 - __clz((tqg + 1) ^ tig);
              pv = s[t][reg] * laml[lvl * 128 + qloc];
            }
            pe[e] = pv;
          }
          pkv[i] = cvtpk(pe[0], pe[1]);
        }
      }
      // redistribute: after swaps pkv[0..3] = B-frag(kstep 2t), pkv[4..7] = B-frag(2t+1)
      plswap(pkv[0], pkv[2]);
      plswap(pkv[1], pkv[3]);
      plswap(pkv[4], pkv[6]);
      plswap(pkv[5], pkv[7]);
      f32x4 f0 = {pkv[0], pkv[1], pkv[2], pkv[3]};
      f32x4 f1 = {pkv[4], pkv[5], pkv[6], pkv[7]};
      snop1();
      int s0c = 4 * t + hi;          // Vs chunk = 2*kstep + hi
#pragma unroll
      for (int dg = 0; dg < 2; ++dg) {
        int row = dg * 32 + q5;
        f32x4 v0 = *(const f32x4*)(Vbase + row * 256 + ((s0c ^ (row & 15)) << 4));
        f32x4 v1 = *(const f32x4*)(Vbase + row * 256 + (((s0c + 2) ^ (row & 15)) << 4));
        if (dg) { mfma32(o1, v0, f0); mfma32(o1, v1, f1); }
        else    { mfma32(o0, v0, f0); mfma32(o0, v1, f1); }
      }
    }
    cur ^= 1;
  }
  mfma_fence();

  // store: O^T col=q (lane), rows d = dg*32 + 8*rq + 4*hi + (0..3)
  int b = bh >> 4, h = bh & 15;
  unsigned short* yrow = Y + ((size_t)(b * TT + tqg)) * DD + h * 64;
#pragma unroll
  for (int dg = 0; dg < 2; ++dg) {
    f32x16 o = dg ? o1 : o0;
#pragma unroll
    for (int rq = 0; rq < 4; ++rq) {
      ushort4 pk;
      pk.x = f2bf(o[4 * rq + 0]); pk.y = f2bf(o[4 * rq + 1]);
      pk.z = f2bf(o[4 * rq + 2]); pk.w = f2bf(o[4 * rq + 3]);
      *(ushort4*)(yrow + dg * 32 + 8 * rq + 4 * hi) = pk;
    }
  }
}

// ---------------- host ----------------

extern "C" void kernel_launch(void* const* d_in, const int* in_sizes, int n_in,
                              void* d_out, int out_size, void* d_ws, size_t ws_size,
                              hipStream_t stream) {
  const float* x  = (const float*)d_in[0];
  const float* Wq = (const float*)d_in[1];
  const float* bq = (const float*)d_in[2];
  const float* Wk = (const float*)d_in[3];
  const float* bk = (const float*)d_in[4];
  const float* Wv = (const float*)d_in[5];
  const float* bv = (const float*)d_in[6];
  const float* Wl = (const float*)d_in[7];
  const float* bl = (const float*)d_in[8];
  const float* Wo = (const float*)d_in[9];
  const float* bo = (const float*)d_in[10];

  char* ws = (char*)d_ws;
  size_t off = 0;
  auto alloc = [&](size_t bytes) { char* p = ws + off; off += bytes; return p; };

  unsigned short* xbf  = (unsigned short*)alloc((size_t)MTOT * DD * 2);      // 8 MB
  unsigned short* Wcat = (unsigned short*)alloc((size_t)4352 * DD * 2);      // 8.9 MB
  unsigned short* Qp   = (unsigned short*)alloc((size_t)MTOT * DD * 2);      // [B,H,T,64]
  unsigned short* Kp   = (unsigned short*)alloc((size_t)MTOT * DD * 2);
  unsigned short* Vtb  = (unsigned short*)alloc((size_t)MTOT * DD * 2);      // [B,H,64,T]
  float*          lamp = (float*)alloc((size_t)32 * TT * 12 * 4);            // [B,H,T,12]
  unsigned short* Y    = (unsigned short*)alloc((size_t)MTOT * DD * 2);
  (void)ws_size; (void)off; (void)in_sizes; (void)n_in; (void)out_size;

  cast_x_kernel<<<MTOT * DD / 4 / 256, 256, 0, stream>>>(x, xbf);
  transpose_all<<<dim3(136, 32), dim3(32, 8), 0, stream>>>(Wq, Wk, Wv, Wl, Wo, Wcat);

  gemm2<128, 0><<<dim3(26, 32), 256, 0, stream>>>(
      xbf, Wcat, bq, bk, bv, bl, Qp, Kp, Vtb, lamp);

  attn_fenwick2<<<dim3(512), 256, 0, stream>>>(Qp, Kp, Vtb, lamp, Y);

  gemm2<64, 1><<<dim3(8, 64), 256, 0, stream>>>(
      Y, Wcat + (size_t)3328 * 1024, bo, nullptr, nullptr, nullptr,
      (float*)d_out, nullptr, nullptr, nullptr);
}